// Round 22
// baseline (1216.157 us; speedup 1.0000x reference)
//
#include <hip/hip_runtime.h>
#include <math.h>

#define G_   8
#define NPG_ 4096
#define HC_  16
#define LAT_ 64
#define FF_  512
#define EDIM_ 3
#define EH_  64
#define NN_  32768
#define EE_  393216
#define EPAD_ (EE_ + NN_ * 8 + 32)   // ranges padded to multiple of 8
#define GS_BLOCKS_ 2048              // persistent-ish grid (8 blocks/CU)

// ---------------- front-end ----------------
__global__ void k_front1(const float* __restrict__ x, const float* __restrict__ w,
                         const float* __restrict__ b, float* __restrict__ h1) {
  int c = blockIdx.x * blockDim.x + threadIdx.x;
  if (c >= FF_) return;
  float acc[G_];
#pragma unroll
  for (int g = 0; g < G_; g++) acc[g] = 0.f;
  for (int r = 0; r < LAT_; r++) {
    float wv = w[r * FF_ + c];
#pragma unroll
    for (int g = 0; g < G_; g++) acc[g] = fmaf(x[g * LAT_ + r], wv, acc[g]);
  }
#pragma unroll
  for (int g = 0; g < G_; g++) h1[g * FF_ + c] = acc[g] + b[c];
}

__global__ __launch_bounds__(512) void k_front2(const float* __restrict__ h1,
                                                const float* __restrict__ w,
                                                const float* __restrict__ b,
                                                float* __restrict__ hn) {
  __shared__ float sh[G_ * FF_];
  for (int i = threadIdx.x; i < G_ * FF_; i += blockDim.x) sh[i] = h1[i];
  __syncthreads();
  int g = threadIdx.x >> 6;
  int lane = threadIdx.x & 63;
  int c = blockIdx.x * 64 + lane;
  const float* shg = &sh[g * FF_];
  float acc = 0.f;
#pragma unroll 8
  for (int r = 0; r < FF_; r++) acc = fmaf(shg[r], w[r * (NPG_ * HC_) + c], acc);
  float v = acc + b[c];
  hn[g * (NPG_ * HC_) + c] = v > 0.f ? v : expm1f(v);
}

// ---------------- counting sort by src (ranges padded to mult of 8) --------
__global__ void k_zero(int* __restrict__ p, int nv) {
  int i = blockIdx.x * blockDim.x + threadIdx.x;
  if (i < nv) p[i] = 0;
}
__global__ void k_hist(const int* __restrict__ key, int* __restrict__ cnt) {
  int e = blockIdx.x * blockDim.x + threadIdx.x;
  if (e < EE_) atomicAdd(&cnt[key[e]], 1);
}
__global__ __launch_bounds__(1024) void k_scan(const int* __restrict__ cnt,
                                               int* __restrict__ rowptr,
                                               int* __restrict__ cursor) {
  __shared__ int part[1024];
  int t = threadIdx.x;
  int base = t * 32;
  int loc[32];
  int s = 0;
#pragma unroll
  for (int i = 0; i < 32; i++) {
    loc[i] = s;
    s += (cnt[base + i] + 7) & ~7;
  }
  part[t] = s;
  __syncthreads();
  for (int off = 1; off < 1024; off <<= 1) {
    int v = (t >= off) ? part[t - off] : 0;
    __syncthreads();
    part[t] += v;
    __syncthreads();
  }
  int pre = (t == 0) ? 0 : part[t - 1];
#pragma unroll
  for (int i = 0; i < 32; i++) {
    int v = pre + loc[i];
    rowptr[base + i] = v;
    cursor[base + i] = v;
  }
  if (t == 1023) rowptr[NN_] = part[1023];
}
// fused scatter: edge data directly at its (padded) src-sorted slot. Pad
// slots hold garbage, are computed but never committed (degree guard).
__global__ void k_scatter(const int* __restrict__ src, const int* __restrict__ dst,
                          const float* __restrict__ ea, int* __restrict__ cursor,
                          float4* __restrict__ eas4) {
  int e = blockIdx.x * blockDim.x + threadIdx.x;
  if (e >= EE_) return;
  int pos = atomicAdd(&cursor[src[e]], 1);
  eas4[pos] = make_float4(ea[e * 3], ea[e * 3 + 1], ea[e * 3 + 2],
                          __int_as_float(dst[e]));
}

// ---------------- weight prep for BOTH convs in one dispatch ----------------
__global__ void k_wprep2(const float* __restrict__ w2a, const float* __restrict__ w1a,
                         const float* __restrict__ b1a, const float* __restrict__ w2b,
                         const float* __restrict__ w1b, const float* __restrict__ b1b,
                         float* __restrict__ W2m0, float4* __restrict__ w1p40,
                         float* __restrict__ W2m1, float4* __restrict__ w1p41) {
  int half = blockIdx.x >> 6;
  const float* w2 = half ? w2b : w2a;
  const float* w1 = half ? w1b : w1a;
  const float* b1 = half ? b1b : b1a;
  float* W2m = half ? W2m1 : W2m0;
  float4* w1p4 = half ? w1p41 : w1p40;
  int idx = (blockIdx.x & 63) * 256 + threadIdx.x;
  if (idx < 16384) {
    int i  = idx >> 10;
    int j4 = (idx >> 8) & 3;
    int l  = (idx >> 2) & 63;
    int c  = idx & 3;
    int q = l >> 4, o = l & 15;
    int h = q * 16 + j4 * 4 + c;
    W2m[idx] = w2[h * 256 + i * 16 + o];
  }
  if (idx < 64) {
    w1p4[idx] = make_float4(w1[idx], w1[64 + idx], w1[128 + idx], b1[idx]);
  }
}

// Fused per-node kernel (grid-stride): optional ELU, nodeinit into hnext,
// T into Tbuf, precM into Mbuf. One wave per 4 nodes per iteration.
__global__ __launch_bounds__(256, 4) void k_node(
    const float* __restrict__ hin, const int do_elu,
    const float* __restrict__ root, const float* __restrict__ bias,
    const float* __restrict__ b2, const float* __restrict__ W2m,
    float* __restrict__ hnode, float* __restrict__ hnext,
    float* __restrict__ Tbuf, float4* __restrict__ Mbuf4) {
  __shared__ float sx[256];
  int tid = threadIdx.x;
  int wave = tid >> 6, l = tid & 63;
  float* swx = &sx[wave * 64];
  const float4* __restrict__ W2m4 = (const float4*)W2m;
  int nd = l >> 4, o = l & 15;

  for (int blk = blockIdx.x; blk < NN_ / 16; blk += GS_BLOCKS_) {
    int n0 = (blk * 4 + wave) * 4;

    float v = hin[n0 * 16 + l];
    if (do_elu) {
      v = v > 0.f ? v : expm1f(v);
      hnode[n0 * 16 + l] = v;
    }
    swx[l] = v;   // wave-local LDS, no barrier needed

    float acc = bias[o];
    float accT = 0.f;
#pragma unroll
    for (int i = 0; i < 16; i++) {
      float xv = swx[nd * 16 + i];
      acc = fmaf(xv, root[i * 16 + o], acc);
      accT = fmaf(xv, b2[i * 16 + o], accT);
    }
    hnext[(n0 + nd) * 16 + o] = acc;
    Tbuf[(n0 + nd) * 16 + o] = accT;

    float4 a0[4], a1[4], a2[4], a3[4];
#pragma unroll
    for (int j4 = 0; j4 < 4; j4++) {
      a0[j4] = make_float4(0.f, 0.f, 0.f, 0.f);
      a1[j4] = make_float4(0.f, 0.f, 0.f, 0.f);
      a2[j4] = make_float4(0.f, 0.f, 0.f, 0.f);
      a3[j4] = make_float4(0.f, 0.f, 0.f, 0.f);
    }
    for (int i = 0; i < 16; i++) {
      float x0 = swx[i];
      float x1 = swx[16 + i];
      float x2 = swx[32 + i];
      float x3 = swx[48 + i];
#pragma unroll
      for (int j4 = 0; j4 < 4; j4++) {
        float4 w = W2m4[i * 256 + j4 * 64 + l];
        a0[j4].x = fmaf(x0, w.x, a0[j4].x); a0[j4].y = fmaf(x0, w.y, a0[j4].y);
        a0[j4].z = fmaf(x0, w.z, a0[j4].z); a0[j4].w = fmaf(x0, w.w, a0[j4].w);
        a1[j4].x = fmaf(x1, w.x, a1[j4].x); a1[j4].y = fmaf(x1, w.y, a1[j4].y);
        a1[j4].z = fmaf(x1, w.z, a1[j4].z); a1[j4].w = fmaf(x1, w.w, a1[j4].w);
        a2[j4].x = fmaf(x2, w.x, a2[j4].x); a2[j4].y = fmaf(x2, w.y, a2[j4].y);
        a2[j4].z = fmaf(x2, w.z, a2[j4].z); a2[j4].w = fmaf(x2, w.w, a2[j4].w);
        a3[j4].x = fmaf(x3, w.x, a3[j4].x); a3[j4].y = fmaf(x3, w.y, a3[j4].y);
        a3[j4].z = fmaf(x3, w.z, a3[j4].z); a3[j4].w = fmaf(x3, w.w, a3[j4].w);
      }
    }
    int s0 = n0 * 256;
#pragma unroll
    for (int j4 = 0; j4 < 4; j4++) Mbuf4[s0 + j4 * 64 + l] = a0[j4];
#pragma unroll
    for (int j4 = 0; j4 < 4; j4++) Mbuf4[s0 + 256 + j4 * 64 + l] = a1[j4];
#pragma unroll
    for (int j4 = 0; j4 < 4; j4++) Mbuf4[s0 + 512 + j4 * 64 + l] = a2[j4];
#pragma unroll
    for (int j4 = 0; j4 < 4; j4++) Mbuf4[s0 + 768 + j4 * 64 + l] = a3[j4];
  }
}

// ---- k_edge helpers ----
__device__ __forceinline__ void phase1(float4 cur, const float4* __restrict__ sw1t,
                                       int hg, int es, float* __restrict__ hid) {
#pragma unroll
  for (int jj = 0; jj < 2; jj++) {
    float4 w0 = sw1t[(jj * 4 + 0) * 8 + hg];
    float4 w1q = sw1t[(jj * 4 + 1) * 8 + hg];
    float4 w2q = sw1t[(jj * 4 + 2) * 8 + hg];
    float4 w3q = sw1t[(jj * 4 + 3) * 8 + hg];
    float4 hv;
    hv.x = fmaxf(fmaf(cur.z, w0.z, fmaf(cur.y, w0.y, fmaf(cur.x, w0.x, w0.w))), 0.f);
    hv.y = fmaxf(fmaf(cur.z, w1q.z, fmaf(cur.y, w1q.y, fmaf(cur.x, w1q.x, w1q.w))), 0.f);
    hv.z = fmaxf(fmaf(cur.z, w2q.z, fmaf(cur.y, w2q.y, fmaf(cur.x, w2q.x, w2q.w))), 0.f);
    hv.w = fmaxf(fmaf(cur.z, w3q.z, fmaf(cur.y, w3q.y, fmaf(cur.x, w3q.x, w3q.w))), 0.f);
    *(float4*)&hid[es * 68 + hg * 8 + jj * 4] = hv;
  }
}

__device__ __forceinline__ void phase2(const float* __restrict__ hid,
                                       const float (&M)[16], float T, float curw,
                                       int k, int limit, int q, int o,
                                       float* __restrict__ hnext) {
  float p[8];
#pragma unroll
  for (int e2 = 0; e2 < 8; e2 += 2) {
    const float4* __restrict__ ha = (const float4*)&hid[e2 * 68 + q * 16];
    const float4* __restrict__ hb = (const float4*)&hid[(e2 + 1) * 68 + q * 16];
    float4 a0 = ha[0], a1 = ha[1], a2 = ha[2], a3 = ha[3];
    float4 b0 = hb[0], b1 = hb[1], b2v = hb[2], b3 = hb[3];
    float pa = 0.f, pb = 0.f;
    pa = fmaf(a0.x, M[0], pa);  pa = fmaf(a0.y, M[1], pa);
    pa = fmaf(a0.z, M[2], pa);  pa = fmaf(a0.w, M[3], pa);
    pa = fmaf(a1.x, M[4], pa);  pa = fmaf(a1.y, M[5], pa);
    pa = fmaf(a1.z, M[6], pa);  pa = fmaf(a1.w, M[7], pa);
    pa = fmaf(a2.x, M[8], pa);  pa = fmaf(a2.y, M[9], pa);
    pa = fmaf(a2.z, M[10], pa); pa = fmaf(a2.w, M[11], pa);
    pa = fmaf(a3.x, M[12], pa); pa = fmaf(a3.y, M[13], pa);
    pa = fmaf(a3.z, M[14], pa); pa = fmaf(a3.w, M[15], pa);
    pb = fmaf(b0.x, M[0], pb);  pb = fmaf(b0.y, M[1], pb);
    pb = fmaf(b0.z, M[2], pb);  pb = fmaf(b0.w, M[3], pb);
    pb = fmaf(b1.x, M[4], pb);  pb = fmaf(b1.y, M[5], pb);
    pb = fmaf(b1.z, M[6], pb);  pb = fmaf(b1.w, M[7], pb);
    pb = fmaf(b2v.x, M[8], pb); pb = fmaf(b2v.y, M[9], pb);
    pb = fmaf(b2v.z, M[10], pb);pb = fmaf(b2v.w, M[11], pb);
    pb = fmaf(b3.x, M[12], pb); pb = fmaf(b3.y, M[13], pb);
    pb = fmaf(b3.z, M[14], pb); pb = fmaf(b3.w, M[15], pb);
    pa += __shfl_xor(pa, 16); pb += __shfl_xor(pb, 16);
    pa += __shfl_xor(pa, 32); pb += __shfl_xor(pb, 32);
    p[e2] = pa; p[e2 + 1] = pb;
  }
  float v1 = (q == 0) ? p[0] : (q == 1) ? p[1] : (q == 2) ? p[2] : p[3];
  float v2 = (q == 0) ? p[4] : (q == 1) ? p[5] : (q == 2) ? p[6] : p[7];
  float dq1 = __shfl(curw, q);
  float dq2 = __shfl(curw, q + 4);
  if (k + q < limit)
    atomicAdd(&hnext[__float_as_int(dq1) * 16 + o], v1 + T);
  if (k + 4 + q < limit)
    atomicAdd(&hnext[__float_as_int(dq2) * 16 + o], v2 + T);
}

// Edge aggregation, two-phase + full-wave commit, grid-stride persistent
// blocks (sw1t staged once per block; dispatch ramp amortized over 16 nodes
// per wave).
__global__ __launch_bounds__(256, 4) void k_edge(
    const int* __restrict__ rowptr, const int* __restrict__ cntr,
    const float4* __restrict__ eas4, const float4* __restrict__ w1p4,
    const float* __restrict__ Tbuf, const float4* __restrict__ Mbuf4,
    float* __restrict__ hnext) {
  __shared__ float4 sw1t[64];          // transposed: sw1t[j8*8+hg] = w1p4[hg*8+j8]
  __shared__ float shid[4 * 544];      // per-wave 8 edges x stride 68
  int tid = threadIdx.x;
  if (tid < 64) sw1t[(tid & 7) * 8 + (tid >> 3)] = w1p4[tid];
  __syncthreads();

  int wave = tid >> 6, l = tid & 63;
  int o = l & 15, q = l >> 4;
  int es = l & 7, hg = l >> 3;
  float* __restrict__ hid = &shid[wave * 544];

  for (int blk = blockIdx.x; blk < NN_ / 4; blk += GS_BLOCKS_) {
    int n = blk * 4 + wave;

    int deg = cntr[n];
    int rs = rowptr[n];
    int mb = n * 256 + l;
    float4 m0 = Mbuf4[mb], m1 = Mbuf4[mb + 64], m2 = Mbuf4[mb + 128],
           m3 = Mbuf4[mb + 192];
    float T = Tbuf[n * 16 + o];

    if (deg <= 0) continue;
    int re = rs + ((deg + 7) & ~7);
    int limit = rs + deg;

    float M[16] = {m0.x, m0.y, m0.z, m0.w, m1.x, m1.y, m1.z, m1.w,
                   m2.x, m2.y, m2.z, m2.w, m3.x, m3.y, m3.z, m3.w};

    float4 cur = eas4[rs + es];
    for (int k = rs; k < re; k += 8) {
      float4 nxt = eas4[k + 8 + es];   // pad slack guarantees in-bounds
      phase1(cur, sw1t, hg, es, hid);
      phase2(hid, M, T, cur.w, k, limit, q, o, hnext);
      cur = nxt;
    }
  }
}

__global__ void k_elu(const float* __restrict__ in, float* __restrict__ out) {
  int idx = blockIdx.x * blockDim.x + threadIdx.x;
  if (idx >= NN_ * HC_) return;
  float v = in[idx];
  out[idx] = v > 0.f ? v : expm1f(v);
}

// ---------------- launch ----------------
extern "C" void kernel_launch(void* const* d_in, const int* in_sizes, int n_in,
                              void* d_out, int out_size, void* d_ws, size_t ws_size,
                              hipStream_t stream) {
  const float* x    = (const float*)d_in[0];
  const int*   ei   = (const int*)d_in[1];
  const float* ea   = (const float*)d_in[2];
  const float* fc2w = (const float*)d_in[3];
  const float* fc2b = (const float*)d_in[4];
  const float* fc1w = (const float*)d_in[5];
  const float* fc1b = (const float*)d_in[6];
  float* out = (float*)d_out;

  float* ws = (float*)d_ws;
  float*  h1     = ws;                               // 4096
  float*  hnode  = h1 + 4096;                        // N*16
  float*  hnext  = hnode + (size_t)NN_ * HC_;        // N*16 + 16 (dummy row)
  float*  W2m0   = hnext + (size_t)NN_ * HC_ + 16;   // 16384
  float*  W2m1   = W2m0 + 16384;                     // 16384
  float4* w1p40  = (float4*)(W2m1 + 16384);          // 256 floats
  float4* w1p41  = w1p40 + 64;                       // 256 floats
  float*  Tbuf   = (float*)(w1p41 + 64);             // N*16
  float4* eas4   = (float4*)(Tbuf + (size_t)NN_ * HC_);  // (EPAD_+32)*4 floats
  float4* Mbuf4  = (float4*)((float*)eas4 + (size_t)(EPAD_ + 32) * 4); // N*1024
  int*    cnt    = (int*)((float*)Mbuf4 + (size_t)NN_ * 1024);
  int*    rowptr = cnt + NN_;                        // N+1
  int*    cursor = rowptr + NN_ + 1;                 // N

  const int* src  = ei;
  const int* dstp = ei + EE_;

  k_front1<<<2, 256, 0, stream>>>(x, fc2w, fc2b, h1);
  k_front2<<<1024, 512, 0, stream>>>(h1, fc1w, fc1b, hnode);

  k_zero<<<(NN_ + 255) / 256, 256, 0, stream>>>(cnt, NN_);
  k_hist<<<(EE_ + 255) / 256, 256, 0, stream>>>(src, cnt);
  k_scan<<<1, 1024, 0, stream>>>(cnt, rowptr, cursor);
  k_scatter<<<(EE_ + 255) / 256, 256, 0, stream>>>(src, dstp, ea, cursor, eas4);

  // both convs' weights prepped in one dispatch, off the conv critical path
  k_wprep2<<<128, 256, 0, stream>>>(
      (const float*)d_in[11], (const float*)d_in[9], (const float*)d_in[10],
      (const float*)d_in[17], (const float*)d_in[15], (const float*)d_in[16],
      W2m0, w1p40, W2m1, w1p41);

  for (int cv = 0; cv < 2; cv++) {
    const float* root = (const float*)d_in[7 + cv * 6];
    const float* cb   = (const float*)d_in[8 + cv * 6];
    const float* b2   = (const float*)d_in[12 + cv * 6];
    float* W2m = cv ? W2m1 : W2m0;
    float4* w1p4 = cv ? w1p41 : w1p40;
    k_node<<<GS_BLOCKS_, 256, 0, stream>>>(cv == 0 ? hnode : hnext, cv,
                                           root, cb, b2, W2m, hnode, hnext,
                                           Tbuf, Mbuf4);
    k_edge<<<GS_BLOCKS_, 256, 0, stream>>>(rowptr, cnt, eas4, w1p4, Tbuf,
                                           Mbuf4, hnext);
  }
  k_elu<<<NN_ * HC_ / 256, 256, 0, stream>>>(hnext, out);
}

// Round 23
// 300.847 us; speedup vs baseline: 4.0424x; 4.0424x over previous
//
#include <hip/hip_runtime.h>
#include <math.h>

#define G_   8
#define NPG_ 4096
#define HC_  16
#define LAT_ 64
#define FF_  512
#define EDIM_ 3
#define EH_  64
#define NN_  32768
#define EE_  393216
#define EPAD_ (EE_ + NN_ * 8 + 32)   // ranges padded to multiple of 8

// ---------------- front-end ----------------
__global__ void k_front1(const float* __restrict__ x, const float* __restrict__ w,
                         const float* __restrict__ b, float* __restrict__ h1) {
  int c = blockIdx.x * blockDim.x + threadIdx.x;
  if (c >= FF_) return;
  float acc[G_];
#pragma unroll
  for (int g = 0; g < G_; g++) acc[g] = 0.f;
  for (int r = 0; r < LAT_; r++) {
    float wv = w[r * FF_ + c];
#pragma unroll
    for (int g = 0; g < G_; g++) acc[g] = fmaf(x[g * LAT_ + r], wv, acc[g]);
  }
#pragma unroll
  for (int g = 0; g < G_; g++) h1[g * FF_ + c] = acc[g] + b[c];
}

__global__ __launch_bounds__(512) void k_front2(const float* __restrict__ h1,
                                                const float* __restrict__ w,
                                                const float* __restrict__ b,
                                                float* __restrict__ hn) {
  __shared__ float sh[G_ * FF_];
  for (int i = threadIdx.x; i < G_ * FF_; i += blockDim.x) sh[i] = h1[i];
  __syncthreads();
  int g = threadIdx.x >> 6;
  int lane = threadIdx.x & 63;
  int c = blockIdx.x * 64 + lane;
  const float* shg = &sh[g * FF_];
  float acc = 0.f;
#pragma unroll 8
  for (int r = 0; r < FF_; r++) acc = fmaf(shg[r], w[r * (NPG_ * HC_) + c], acc);
  float v = acc + b[c];
  hn[g * (NPG_ * HC_) + c] = v > 0.f ? v : expm1f(v);
}

// ---------------- counting sort by src (ranges padded to mult of 8) --------
__global__ void k_zero(int* __restrict__ p, int nv) {
  int i = blockIdx.x * blockDim.x + threadIdx.x;
  if (i < nv) p[i] = 0;
}
__global__ void k_hist(const int* __restrict__ key, int* __restrict__ cnt) {
  int e = blockIdx.x * blockDim.x + threadIdx.x;
  if (e < EE_) atomicAdd(&cnt[key[e]], 1);
}
__global__ __launch_bounds__(1024) void k_scan(const int* __restrict__ cnt,
                                               int* __restrict__ rowptr,
                                               int* __restrict__ cursor) {
  __shared__ int part[1024];
  int t = threadIdx.x;
  int base = t * 32;
  int loc[32];
  int s = 0;
#pragma unroll
  for (int i = 0; i < 32; i++) {
    loc[i] = s;
    s += (cnt[base + i] + 7) & ~7;
  }
  part[t] = s;
  __syncthreads();
  for (int off = 1; off < 1024; off <<= 1) {
    int v = (t >= off) ? part[t - off] : 0;
    __syncthreads();
    part[t] += v;
    __syncthreads();
  }
  int pre = (t == 0) ? 0 : part[t - 1];
#pragma unroll
  for (int i = 0; i < 32; i++) {
    int v = pre + loc[i];
    rowptr[base + i] = v;
    cursor[base + i] = v;
  }
  if (t == 1023) rowptr[NN_] = part[1023];
}
// fused scatter: edge data directly at its (padded) src-sorted slot. Pad
// slots hold garbage, are computed but never committed (degree guard).
__global__ void k_scatter(const int* __restrict__ src, const int* __restrict__ dst,
                          const float* __restrict__ ea, int* __restrict__ cursor,
                          float4* __restrict__ eas4) {
  int e = blockIdx.x * blockDim.x + threadIdx.x;
  if (e >= EE_) return;
  int pos = atomicAdd(&cursor[src[e]], 1);
  eas4[pos] = make_float4(ea[e * 3], ea[e * 3 + 1], ea[e * 3 + 2],
                          __int_as_float(dst[e]));
}

// ---------------- weight prep for BOTH convs in one dispatch ----------------
__global__ void k_wprep2(const float* __restrict__ w2a, const float* __restrict__ w1a,
                         const float* __restrict__ b1a, const float* __restrict__ w2b,
                         const float* __restrict__ w1b, const float* __restrict__ b1b,
                         float* __restrict__ W2m0, float4* __restrict__ w1p40,
                         float* __restrict__ W2m1, float4* __restrict__ w1p41) {
  int half = blockIdx.x >> 6;
  const float* w2 = half ? w2b : w2a;
  const float* w1 = half ? w1b : w1a;
  const float* b1 = half ? b1b : b1a;
  float* W2m = half ? W2m1 : W2m0;
  float4* w1p4 = half ? w1p41 : w1p40;
  int idx = (blockIdx.x & 63) * 256 + threadIdx.x;
  if (idx < 16384) {
    int i  = idx >> 10;
    int j4 = (idx >> 8) & 3;
    int l  = (idx >> 2) & 63;
    int c  = idx & 3;
    int q = l >> 4, o = l & 15;
    int h = q * 16 + j4 * 4 + c;
    W2m[idx] = w2[h * 256 + i * 16 + o];
  }
  if (idx < 64) {
    w1p4[idx] = make_float4(w1[idx], w1[64 + idx], w1[128 + idx], b1[idx]);
  }
}

// Fused per-node kernel: optional ELU, nodeinit into hnext, T into Tbuf,
// precM into Mbuf. One wave per 4 nodes; x staged in wave-local LDS.
__global__ __launch_bounds__(256, 4) void k_node(
    const float* __restrict__ hin, const int do_elu,
    const float* __restrict__ root, const float* __restrict__ bias,
    const float* __restrict__ b2, const float* __restrict__ W2m,
    float* __restrict__ hnode, float* __restrict__ hnext,
    float* __restrict__ Tbuf, float4* __restrict__ Mbuf4) {
  __shared__ float sx[256];
  int tid = threadIdx.x;
  int wave = tid >> 6, l = tid & 63;
  int n0 = (blockIdx.x * 4 + wave) * 4;
  float* swx = &sx[wave * 64];

  float v = hin[n0 * 16 + l];
  if (do_elu) {
    v = v > 0.f ? v : expm1f(v);
    hnode[n0 * 16 + l] = v;
  }
  swx[l] = v;

  int nd = l >> 4, o = l & 15;
  float acc = bias[o];
  float accT = 0.f;
#pragma unroll
  for (int i = 0; i < 16; i++) {
    float xv = swx[nd * 16 + i];
    acc = fmaf(xv, root[i * 16 + o], acc);
    accT = fmaf(xv, b2[i * 16 + o], accT);
  }
  hnext[(n0 + nd) * 16 + o] = acc;
  Tbuf[(n0 + nd) * 16 + o] = accT;

  const float4* __restrict__ W2m4 = (const float4*)W2m;
  float4 a0[4], a1[4], a2[4], a3[4];
#pragma unroll
  for (int j4 = 0; j4 < 4; j4++) {
    a0[j4] = make_float4(0.f, 0.f, 0.f, 0.f);
    a1[j4] = make_float4(0.f, 0.f, 0.f, 0.f);
    a2[j4] = make_float4(0.f, 0.f, 0.f, 0.f);
    a3[j4] = make_float4(0.f, 0.f, 0.f, 0.f);
  }
  for (int i = 0; i < 16; i++) {
    float x0 = swx[i];
    float x1 = swx[16 + i];
    float x2 = swx[32 + i];
    float x3 = swx[48 + i];
#pragma unroll
    for (int j4 = 0; j4 < 4; j4++) {
      float4 w = W2m4[i * 256 + j4 * 64 + l];
      a0[j4].x = fmaf(x0, w.x, a0[j4].x); a0[j4].y = fmaf(x0, w.y, a0[j4].y);
      a0[j4].z = fmaf(x0, w.z, a0[j4].z); a0[j4].w = fmaf(x0, w.w, a0[j4].w);
      a1[j4].x = fmaf(x1, w.x, a1[j4].x); a1[j4].y = fmaf(x1, w.y, a1[j4].y);
      a1[j4].z = fmaf(x1, w.z, a1[j4].z); a1[j4].w = fmaf(x1, w.w, a1[j4].w);
      a2[j4].x = fmaf(x2, w.x, a2[j4].x); a2[j4].y = fmaf(x2, w.y, a2[j4].y);
      a2[j4].z = fmaf(x2, w.z, a2[j4].z); a2[j4].w = fmaf(x2, w.w, a2[j4].w);
      a3[j4].x = fmaf(x3, w.x, a3[j4].x); a3[j4].y = fmaf(x3, w.y, a3[j4].y);
      a3[j4].z = fmaf(x3, w.z, a3[j4].z); a3[j4].w = fmaf(x3, w.w, a3[j4].w);
    }
  }
  int s0 = n0 * 256;
#pragma unroll
  for (int j4 = 0; j4 < 4; j4++) Mbuf4[s0 + j4 * 64 + l] = a0[j4];
#pragma unroll
  for (int j4 = 0; j4 < 4; j4++) Mbuf4[s0 + 256 + j4 * 64 + l] = a1[j4];
#pragma unroll
  for (int j4 = 0; j4 < 4; j4++) Mbuf4[s0 + 512 + j4 * 64 + l] = a2[j4];
#pragma unroll
  for (int j4 = 0; j4 < 4; j4++) Mbuf4[s0 + 768 + j4 * 64 + l] = a3[j4];
}

// Edge aggregation, two-phase + full-wave commit. Chunk = 8 edges.
// Phase 1: lane (es=l&7, hg=l>>3) computes hidden once -> LDS.
// Phase 2: lane (o,q) dots each edge's q-quarter vs register M, butterfly
//   reduces, BUFFERS the 8 sums, then commits all 8 edges in 2 atomic
//   instructions with all 64 lanes active (lane-group q -> edges k+q, k+4+q).
__global__ __launch_bounds__(256, 4) void k_edge(
    const int* __restrict__ rowptr, const int* __restrict__ cntr,
    const float4* __restrict__ eas4, const float4* __restrict__ w1p4,
    const float* __restrict__ Tbuf, const float4* __restrict__ Mbuf4,
    float* __restrict__ hnext) {
  __shared__ float4 sw1t[64];          // transposed: sw1t[j8*8+hg] = w1p4[hg*8+j8]
  __shared__ float shid[4 * 544];      // per-wave 8 edges x stride 68
  int tid = threadIdx.x;
  if (tid < 64) sw1t[(tid & 7) * 8 + (tid >> 3)] = w1p4[tid];
  __syncthreads();

  int wave = tid >> 6, l = tid & 63;
  int o = l & 15, q = l >> 4;
  int es = l & 7, hg = l >> 3;
  int n = blockIdx.x * 4 + wave;

  int deg = cntr[n];
  if (deg <= 0) return;
  int rs = rowptr[n];
  int re = rs + ((deg + 7) & ~7);
  int limit = rs + deg;

  float* __restrict__ hid = &shid[wave * 544];

  int mb = n * 256 + l;
  float4 m0 = Mbuf4[mb], m1 = Mbuf4[mb + 64], m2 = Mbuf4[mb + 128],
         m3 = Mbuf4[mb + 192];
  float M[16] = {m0.x, m0.y, m0.z, m0.w, m1.x, m1.y, m1.z, m1.w,
                 m2.x, m2.y, m2.z, m2.w, m3.x, m3.y, m3.z, m3.w};

  float T = Tbuf[n * 16 + o];

  float4 cur = eas4[rs + es];
  for (int k = rs; k < re; k += 8) {
    float4 nxt = eas4[k + 8 + es];

    // phase 1: hidden for edge es, h = hg*8 + jj*4 + c (computed once)
#pragma unroll
    for (int jj = 0; jj < 2; jj++) {
      float4 w0 = sw1t[(jj * 4 + 0) * 8 + hg];
      float4 w1q = sw1t[(jj * 4 + 1) * 8 + hg];
      float4 w2q = sw1t[(jj * 4 + 2) * 8 + hg];
      float4 w3q = sw1t[(jj * 4 + 3) * 8 + hg];
      float4 hv;
      hv.x = fmaxf(fmaf(cur.z, w0.z, fmaf(cur.y, w0.y, fmaf(cur.x, w0.x, w0.w))), 0.f);
      hv.y = fmaxf(fmaf(cur.z, w1q.z, fmaf(cur.y, w1q.y, fmaf(cur.x, w1q.x, w1q.w))), 0.f);
      hv.z = fmaxf(fmaf(cur.z, w2q.z, fmaf(cur.y, w2q.y, fmaf(cur.x, w2q.x, w2q.w))), 0.f);
      hv.w = fmaxf(fmaf(cur.z, w3q.z, fmaf(cur.y, w3q.y, fmaf(cur.x, w3q.x, w3q.w))), 0.f);
      *(float4*)&hid[es * 68 + hg * 8 + jj * 4] = hv;
    }

    // phase 2: broadcast reads + dot + butterfly; buffer the 8 sums
    float p[8];
#pragma unroll
    for (int e2 = 0; e2 < 8; e2 += 2) {
      const float4* __restrict__ ha = (const float4*)&hid[e2 * 68 + q * 16];
      const float4* __restrict__ hb = (const float4*)&hid[(e2 + 1) * 68 + q * 16];
      float4 a0 = ha[0], a1 = ha[1], a2 = ha[2], a3 = ha[3];
      float4 b0 = hb[0], b1 = hb[1], b2v = hb[2], b3 = hb[3];
      float pa = 0.f, pb = 0.f;
      pa = fmaf(a0.x, M[0], pa);  pa = fmaf(a0.y, M[1], pa);
      pa = fmaf(a0.z, M[2], pa);  pa = fmaf(a0.w, M[3], pa);
      pa = fmaf(a1.x, M[4], pa);  pa = fmaf(a1.y, M[5], pa);
      pa = fmaf(a1.z, M[6], pa);  pa = fmaf(a1.w, M[7], pa);
      pa = fmaf(a2.x, M[8], pa);  pa = fmaf(a2.y, M[9], pa);
      pa = fmaf(a2.z, M[10], pa); pa = fmaf(a2.w, M[11], pa);
      pa = fmaf(a3.x, M[12], pa); pa = fmaf(a3.y, M[13], pa);
      pa = fmaf(a3.z, M[14], pa); pa = fmaf(a3.w, M[15], pa);
      pb = fmaf(b0.x, M[0], pb);  pb = fmaf(b0.y, M[1], pb);
      pb = fmaf(b0.z, M[2], pb);  pb = fmaf(b0.w, M[3], pb);
      pb = fmaf(b1.x, M[4], pb);  pb = fmaf(b1.y, M[5], pb);
      pb = fmaf(b1.z, M[6], pb);  pb = fmaf(b1.w, M[7], pb);
      pb = fmaf(b2v.x, M[8], pb); pb = fmaf(b2v.y, M[9], pb);
      pb = fmaf(b2v.z, M[10], pb);pb = fmaf(b2v.w, M[11], pb);
      pb = fmaf(b3.x, M[12], pb); pb = fmaf(b3.y, M[13], pb);
      pb = fmaf(b3.z, M[14], pb); pb = fmaf(b3.w, M[15], pb);
      pa += __shfl_xor(pa, 16); pb += __shfl_xor(pb, 16);
      pa += __shfl_xor(pa, 32); pb += __shfl_xor(pb, 32);
      p[e2] = pa; p[e2 + 1] = pb;
    }

    // full-wave commit: lane-group q commits edges k+q and k+4+q
    float curw = cur.w;
    float v1 = (q == 0) ? p[0] : (q == 1) ? p[1] : (q == 2) ? p[2] : p[3];
    float v2 = (q == 0) ? p[4] : (q == 1) ? p[5] : (q == 2) ? p[6] : p[7];
    float dq1 = __shfl(curw, q);
    float dq2 = __shfl(curw, q + 4);
    if (k + q < limit)
      atomicAdd(&hnext[__float_as_int(dq1) * 16 + o], v1 + T);
    if (k + 4 + q < limit)
      atomicAdd(&hnext[__float_as_int(dq2) * 16 + o], v2 + T);

    cur = nxt;
  }
}

__global__ void k_elu(const float* __restrict__ in, float* __restrict__ out) {
  int idx = blockIdx.x * blockDim.x + threadIdx.x;
  if (idx >= NN_ * HC_) return;
  float v = in[idx];
  out[idx] = v > 0.f ? v : expm1f(v);
}

// ---------------- launch ----------------
extern "C" void kernel_launch(void* const* d_in, const int* in_sizes, int n_in,
                              void* d_out, int out_size, void* d_ws, size_t ws_size,
                              hipStream_t stream) {
  const float* x    = (const float*)d_in[0];
  const int*   ei   = (const int*)d_in[1];
  const float* ea   = (const float*)d_in[2];
  const float* fc2w = (const float*)d_in[3];
  const float* fc2b = (const float*)d_in[4];
  const float* fc1w = (const float*)d_in[5];
  const float* fc1b = (const float*)d_in[6];
  float* out = (float*)d_out;

  float* ws = (float*)d_ws;
  float*  h1     = ws;                               // 4096
  float*  hnode  = h1 + 4096;                        // N*16
  float*  hnext  = hnode + (size_t)NN_ * HC_;        // N*16 + 16 (dummy row)
  float*  W2m0   = hnext + (size_t)NN_ * HC_ + 16;   // 16384
  float*  W2m1   = W2m0 + 16384;                     // 16384
  float4* w1p40  = (float4*)(W2m1 + 16384);          // 256 floats
  float4* w1p41  = w1p40 + 64;                       // 256 floats
  float*  Tbuf   = (float*)(w1p41 + 64);             // N*16
  float4* eas4   = (float4*)(Tbuf + (size_t)NN_ * HC_);  // (EPAD_+32)*4 floats
  float4* Mbuf4  = (float4*)((float*)eas4 + (size_t)(EPAD_ + 32) * 4); // N*1024
  int*    cnt    = (int*)((float*)Mbuf4 + (size_t)NN_ * 1024);
  int*    rowptr = cnt + NN_;                        // N+1
  int*    cursor = rowptr + NN_ + 1;                 // N

  const int* src  = ei;
  const int* dstp = ei + EE_;

  k_front1<<<2, 256, 0, stream>>>(x, fc2w, fc2b, h1);
  k_front2<<<1024, 512, 0, stream>>>(h1, fc1w, fc1b, hnode);

  k_zero<<<(NN_ + 255) / 256, 256, 0, stream>>>(cnt, NN_);
  k_hist<<<(EE_ + 255) / 256, 256, 0, stream>>>(src, cnt);
  k_scan<<<1, 1024, 0, stream>>>(cnt, rowptr, cursor);
  k_scatter<<<(EE_ + 255) / 256, 256, 0, stream>>>(src, dstp, ea, cursor, eas4);

  // both convs' weights prepped in one dispatch, off the conv critical path
  k_wprep2<<<128, 256, 0, stream>>>(
      (const float*)d_in[11], (const float*)d_in[9], (const float*)d_in[10],
      (const float*)d_in[17], (const float*)d_in[15], (const float*)d_in[16],
      W2m0, w1p40, W2m1, w1p41);

  for (int cv = 0; cv < 2; cv++) {
    const float* root = (const float*)d_in[7 + cv * 6];
    const float* cb   = (const float*)d_in[8 + cv * 6];
    const float* b2   = (const float*)d_in[12 + cv * 6];
    float* W2m = cv ? W2m1 : W2m0;
    float4* w1p4 = cv ? w1p41 : w1p40;
    k_node<<<NN_ / 16, 256, 0, stream>>>(cv == 0 ? hnode : hnext, cv,
                                         root, cb, b2, W2m, hnode, hnext,
                                         Tbuf, Mbuf4);
    k_edge<<<NN_ / 4, 256, 0, stream>>>(rowptr, cnt, eas4, w1p4, Tbuf,
                                        Mbuf4, hnext);
  }
  k_elu<<<NN_ * HC_ / 256, 256, 0, stream>>>(hnext, out);
}